// Round 12
// baseline (17.135 us; speedup 1.0000x reference)
//
#include <hip/hip_runtime.h>
#include <math.h>

#define ALPHA 0.001f
#define BETA  0.001f
#define EPS   1e-32f

constexpr int BLOCK  = 256;
constexpr int ITILE  = 4;      // i-rows per thread (contiguous)
constexpr int JCHUNK = 512;    // j-tile staged as f16 in LDS (1 KB)
// Pad value for compacted-row tail: exactly representable in f16 (60000=32*1875).
// Pad row accumulates JCHUNK/2 fdot2 adds of 120000 -> partials are multiples of
// 120000 (div. by 32) up to 30.72M < 2^29, each exactly representable in f32, and
// the -(JCHUNK*60000) correction (also exact) cancels EXACTLY to 0.0f.
#define PADF 60000.0f

typedef _Float16 f16x2 __attribute__((ext_vector_type(2)));

// acc += a.x + a.y  via v_dot2_f32_f16(a, (1,1), acc)
__device__ __forceinline__ float dot2acc(f16x2 a, float c) {
#if __has_builtin(__builtin_amdgcn_fdot2)
    const f16x2 one2 = {(_Float16)1.0f, (_Float16)1.0f};
    return __builtin_amdgcn_fdot2(a, one2, c, false);
#else
    return c + (float)a.x + (float)a.y;
#endif
}

// Inner sweep over the j-chunk for K compacted i-rows per thread.
// Returns Sum_u [ Sum_j max(e_j, e_u) - JCHUNK * e_u ]  (all rows have ev=1).
// Rows with index >= C are padded with PADF -> contribution exactly 0.
template<int K>
__device__ __forceinline__ float inner_loop(const _Float16* __restrict__ se,
                                            const _Float16* __restrict__ ce,
                                            int tid, int C) {
    float acc[K], eih[K];
    f16x2 ei2[K];
    #pragma unroll
    for (int u = 0; u < K; ++u) {
        int r = u * BLOCK + tid;                 // only u==K-1 can exceed C
        _Float16 h = (r < C) ? ce[r] : (_Float16)PADF;
        ei2[u] = (f16x2){h, h};
        eih[u] = (float)h;
        acc[u] = 0.f;
    }
    const uint4* sev = (const uint4*)se;         // 8 halves per ds_read_b128
    #pragma unroll 4
    for (int k = 0; k < JCHUNK / 8; ++k) {
        uint4 raw = sev[k];
        f16x2 h0 = __builtin_bit_cast(f16x2, raw.x);
        f16x2 h1 = __builtin_bit_cast(f16x2, raw.y);
        f16x2 h2 = __builtin_bit_cast(f16x2, raw.z);
        f16x2 h3 = __builtin_bit_cast(f16x2, raw.w);
        #pragma unroll
        for (int u = 0; u < K; ++u) {
            acc[u] = dot2acc(__builtin_elementwise_max(h0, ei2[u]), acc[u]);
            acc[u] = dot2acc(__builtin_elementwise_max(h1, ei2[u]), acc[u]);
            acc[u] = dot2acc(__builtin_elementwise_max(h2, ei2[u]), acc[u]);
            acc[u] = dot2acc(__builtin_elementwise_max(h3, ei2[u]), acc[u]);
        }
    }
    float loss = 0.f;
    #pragma unroll
    for (int u = 0; u < K; ++u)
        loss += acc[u] - (float)JCHUNK * eih[u];
    return loss;
}

// Heavy kernel: per (i-superblock=1024 rows, j-chunk=512) block.
// 1) compute e for own 4 contiguous rows (float4 loads) + penalty partial
// 2) compact rows with events==1 into LDS (index-ordered scan -> deterministic)
// 3) switch(K=ceil(C/256)) -> templated inner loop (~50% of rows carry events).
// nib=16/njc=32 split minimizes redundant e-computation (786K vs 1.18M rows)
// while keeping 512 blocks = 2/CU and K_avg ~= 2.
__global__ __launch_bounds__(BLOCK) void pair_fused_kernel(
        const float* __restrict__ log_h,
        const float* __restrict__ dur,
        const float* __restrict__ events,
        float* __restrict__ lossp,   // nib*njc floats
        float* __restrict__ penp,    // nib floats
        int nib, int n) {
    __shared__ alignas(16) _Float16 se[JCHUNK];
    __shared__ alignas(16) _Float16 ce[BLOCK * ITILE];   // compacted e_i (2 KB)
    __shared__ int wt[BLOCK / 64];
    const int tid = threadIdx.x;
    const int bid = blockIdx.x;
    const int bx  = bid % nib;
    const int by  = bid / nib;

    // i-prologue: 4 contiguous rows per thread -> 1 float4 load per array
    const int i0 = bx * (BLOCK * ITILE);
    const int iv = i0 / 4 + tid;
    float4 lh4 = ((const float4*)log_h)[iv];
    float4 du4 = ((const float4*)dur)[iv];
    float4 ev4 = ((const float4*)events)[iv];

    // stage j-chunk: e_j computed inline, stored f16 (2 rows/thread)
    {
        int j = by * JCHUNK + tid;
        float ejf0 = __logf(dur[j] + EPS) - log_h[j];
        float ejf1 = __logf(dur[j + BLOCK] + EPS) - log_h[j + BLOCK];
        se[tid]         = (_Float16)ejf0;
        se[tid + BLOCK] = (_Float16)ejf1;
    }

    _Float16 h[ITILE];
    bool flag[ITILE];
    float pen = 0.f;
    int cnt = 0;
    {
        const float lhs[4] = {lh4.x, lh4.y, lh4.z, lh4.w};
        const float dus[4] = {du4.x, du4.y, du4.z, du4.w};
        const float evs[4] = {ev4.x, ev4.y, ev4.z, ev4.w};
        #pragma unroll
        for (int u = 0; u < ITILE; ++u) {
            float lh = lhs[u];
            float ei = __logf(dus[u] + EPS) - lh;
            h[u] = (_Float16)ei;
            flag[u] = (evs[u] != 0.0f);
            cnt += flag[u] ? 1 : 0;
            pen += ALPHA * ei * ei + BETA * lh * lh;
        }
    }

    // block-wide exclusive scan of cnt (index-ordered -> deterministic)
    int inc = cnt;
    #pragma unroll
    for (int off = 1; off < 64; off <<= 1) {
        int y = __shfl_up(inc, off);
        if ((tid & 63) >= off) inc += y;
    }
    if ((tid & 63) == 63) wt[tid >> 6] = inc;
    __syncthreads();
    int wbase = 0;
    #pragma unroll
    for (int w = 0; w < BLOCK / 64; ++w)
        wbase += (w < (tid >> 6)) ? wt[w] : 0;
    const int C = wt[0] + wt[1] + wt[2] + wt[3];

    // scatter this thread's event-rows into ce[base..]
    {
        int p = wbase + inc - cnt;
        #pragma unroll
        for (int u = 0; u < ITILE; ++u) {
            if (flag[u]) { ce[p] = h[u]; ++p; }
        }
    }
    __syncthreads();

    const int K = (C + BLOCK - 1) >> 8;      // ceil(C/256), uniform across block
    float loss = 0.f;
    switch (K) {
        case 1: loss = inner_loop<1>(se, ce, tid, C); break;
        case 2: loss = inner_loop<2>(se, ce, tid, C); break;
        case 3: loss = inner_loop<3>(se, ce, tid, C); break;
        case 4: loss = inner_loop<4>(se, ce, tid, C); break;
        default: break;                       // K==0: no event rows
    }

    for (int off = 32; off; off >>= 1) {
        loss += __shfl_down(loss, off);
        pen  += __shfl_down(pen, off);
    }
    __shared__ float wl[BLOCK / 64], wp[BLOCK / 64];
    if ((tid & 63) == 0) { wl[tid >> 6] = loss; wp[tid >> 6] = pen; }
    __syncthreads();
    if (tid == 0) {
        float tl = 0.f, tp = 0.f;
        for (int w = 0; w < BLOCK / 64; ++w) { tl += wl[w]; tp += wp[w]; }
        lossp[by * nib + bx] = tl;
        if (by == 0) penp[bx] = tp;
    }
}

// Tiny finalize node: fixed-order reduce of partials (deterministic).
__global__ void finalize_kernel(const float* __restrict__ lossp, int nloss,
                                const float* __restrict__ penp, int npen,
                                float* __restrict__ out, int n) {
    const int tid = threadIdx.x;
    const float invn  = 1.0f / (float)n;
    const float invn2 = invn * invn;
    float v = 0.f;
    for (int k = tid; k < nloss; k += BLOCK) v += lossp[k] * invn2;
    for (int k = tid; k < npen;  k += BLOCK) v += penp[k] * invn;
    for (int off = 32; off; off >>= 1) v += __shfl_down(v, off);
    __shared__ float ws[BLOCK / 64];
    if ((tid & 63) == 0) ws[tid >> 6] = v;
    __syncthreads();
    if (tid == 0) {
        float t = 0.f;
        for (int w = 0; w < BLOCK / 64; ++w) t += ws[w];
        out[0] = t;
    }
}

extern "C" void kernel_launch(void* const* d_in, const int* in_sizes, int n_in,
                              void* d_out, int out_size, void* d_ws, size_t ws_size,
                              hipStream_t stream) {
    const float* log_h  = (const float*)d_in[0];
    const float* dur    = (const float*)d_in[1];
    const float* events = (const float*)d_in[2];
    float* out = (float*)d_out;
    const int n = in_sizes[1];                        // 16384

    const int nib = n / (BLOCK * ITILE);              // 16 i-superblocks
    const int njc = n / JCHUNK;                       // 32 j-chunks
    const int nblocks = nib * njc;                    // 512 blocks = 2/CU

    float* lossp = (float*)d_ws;                      // nblocks floats
    float* penp  = lossp + nblocks;                   // nib floats

    pair_fused_kernel<<<nblocks, BLOCK, 0, stream>>>(log_h, dur, events,
                                                     lossp, penp, nib, n);
    finalize_kernel<<<1, BLOCK, 0, stream>>>(lossp, nblocks, penp, nib, out, n);
}

// Round 13
// 15.885 us; speedup vs baseline: 1.0787x; 1.0787x over previous
//
#include <hip/hip_runtime.h>
#include <math.h>

#define ALPHA 0.001f
#define BETA  0.001f
#define EPS   1e-32f

constexpr int BLOCK  = 256;
constexpr int ITILE  = 8;      // i-rows per thread (contiguous)
constexpr int JCHUNK = 256;    // j-tile staged as f16 in LDS (512 B)
// Pad value for compacted-row tail: exactly representable in f16 (60000=32*1875),
// and 128 fdot2 adds of 120000 reach 15,360,000 < 2^24, so the accumulated sum
// and the -256*60000 correction cancel EXACTLY to 0.0f in f32.
#define PADF 60000.0f

typedef _Float16 f16x2 __attribute__((ext_vector_type(2)));

// acc += a.x + a.y  via v_dot2_f32_f16(a, (1,1), acc)
__device__ __forceinline__ float dot2acc(f16x2 a, float c) {
#if __has_builtin(__builtin_amdgcn_fdot2)
    const f16x2 one2 = {(_Float16)1.0f, (_Float16)1.0f};
    return __builtin_amdgcn_fdot2(a, one2, c, false);
#else
    return c + (float)a.x + (float)a.y;
#endif
}

// Inner sweep over the j-chunk for K compacted i-rows per thread.
// Returns Sum_u [ Sum_j max(e_j, e_u) - JCHUNK * e_u ]  (all rows have ev=1).
// Rows with index >= C are padded with PADF -> contribution exactly 0.
template<int K>
__device__ __forceinline__ float inner_loop(const _Float16* __restrict__ se,
                                            const _Float16* __restrict__ ce,
                                            int tid, int C) {
    float acc[K], eih[K];
    f16x2 ei2[K];
    #pragma unroll
    for (int u = 0; u < K; ++u) {
        int r = u * BLOCK + tid;                 // only u==K-1 can exceed C
        _Float16 h = (r < C) ? ce[r] : (_Float16)PADF;
        ei2[u] = (f16x2){h, h};
        eih[u] = (float)h;
        acc[u] = 0.f;
    }
    const uint4* sev = (const uint4*)se;         // 8 halves per ds_read_b128
    #pragma unroll 4
    for (int k = 0; k < JCHUNK / 8; ++k) {
        uint4 raw = sev[k];
        f16x2 h0 = __builtin_bit_cast(f16x2, raw.x);
        f16x2 h1 = __builtin_bit_cast(f16x2, raw.y);
        f16x2 h2 = __builtin_bit_cast(f16x2, raw.z);
        f16x2 h3 = __builtin_bit_cast(f16x2, raw.w);
        #pragma unroll
        for (int u = 0; u < K; ++u) {
            acc[u] = dot2acc(__builtin_elementwise_max(h0, ei2[u]), acc[u]);
            acc[u] = dot2acc(__builtin_elementwise_max(h1, ei2[u]), acc[u]);
            acc[u] = dot2acc(__builtin_elementwise_max(h2, ei2[u]), acc[u]);
            acc[u] = dot2acc(__builtin_elementwise_max(h3, ei2[u]), acc[u]);
        }
    }
    float loss = 0.f;
    #pragma unroll
    for (int u = 0; u < K; ++u)
        loss += acc[u] - (float)JCHUNK * eih[u];
    return loss;
}

// Heavy kernel: per (i-superblock=2048 rows, j-chunk=256) block.
// 1) compute e for own 8 contiguous rows (float4 loads) + penalty partial
// 2) compact rows with events==1 into LDS (index-ordered scan -> deterministic)
// 3) switch(K=ceil(C/256)) -> templated inner loop, ~halving pair work since
//    only ~50% of rows carry events. No ev multiply needed after compaction.
// Geometry r11 (ITILE=8, JCHUNK=256): measured optimum. r12's nib=16/JCHUNK=512
// regressed (+1.2us): K-quantum is 256 rows regardless of JCHUNK, so bigger
// JCHUNK inflates quantization slack (E[ceil(C/256)]*JCHUNK: 1152 -> 1280).
__global__ __launch_bounds__(BLOCK) void pair_fused_kernel(
        const float* __restrict__ log_h,
        const float* __restrict__ dur,
        const float* __restrict__ events,
        float* __restrict__ lossp,   // nib*njc floats
        float* __restrict__ penp,    // nib floats
        int nib, int n) {
    __shared__ alignas(16) _Float16 se[JCHUNK];
    __shared__ alignas(16) _Float16 ce[BLOCK * ITILE];   // compacted e_i (4 KB)
    __shared__ int wt[BLOCK / 64];
    const int tid = threadIdx.x;
    const int bid = blockIdx.x;
    const int bx  = bid % nib;
    const int by  = bid / nib;

    // i-prologue: 8 contiguous rows per thread -> 2 float4 loads per array
    const int i0 = bx * (BLOCK * ITILE);
    const int iv = i0 / 4 + tid * 2;
    float4 lh4a = ((const float4*)log_h)[iv],  lh4b = ((const float4*)log_h)[iv + 1];
    float4 du4a = ((const float4*)dur)[iv],    du4b = ((const float4*)dur)[iv + 1];
    float4 ev4a = ((const float4*)events)[iv], ev4b = ((const float4*)events)[iv + 1];

    // stage j-chunk: e_j computed inline, stored f16 (JCHUNK == BLOCK)
    {
        int j = by * JCHUNK + tid;
        float ejf = __logf(dur[j] + EPS) - log_h[j];
        se[tid] = (_Float16)ejf;
    }

    _Float16 h[ITILE];
    bool flag[ITILE];
    float pen = 0.f;
    int cnt = 0;
    {
        const float lhs[8] = {lh4a.x, lh4a.y, lh4a.z, lh4a.w,
                              lh4b.x, lh4b.y, lh4b.z, lh4b.w};
        const float dus[8] = {du4a.x, du4a.y, du4a.z, du4a.w,
                              du4b.x, du4b.y, du4b.z, du4b.w};
        const float evs[8] = {ev4a.x, ev4a.y, ev4a.z, ev4a.w,
                              ev4b.x, ev4b.y, ev4b.z, ev4b.w};
        #pragma unroll
        for (int u = 0; u < ITILE; ++u) {
            float lh = lhs[u];
            float ei = __logf(dus[u] + EPS) - lh;
            h[u] = (_Float16)ei;
            flag[u] = (evs[u] != 0.0f);
            cnt += flag[u] ? 1 : 0;
            pen += ALPHA * ei * ei + BETA * lh * lh;
        }
    }

    // block-wide exclusive scan of cnt (index-ordered -> deterministic)
    int inc = cnt;
    #pragma unroll
    for (int off = 1; off < 64; off <<= 1) {
        int y = __shfl_up(inc, off);
        if ((tid & 63) >= off) inc += y;
    }
    if ((tid & 63) == 63) wt[tid >> 6] = inc;
    __syncthreads();
    int wbase = 0;
    #pragma unroll
    for (int w = 0; w < BLOCK / 64; ++w)
        wbase += (w < (tid >> 6)) ? wt[w] : 0;
    const int C = wt[0] + wt[1] + wt[2] + wt[3];

    // scatter this thread's event-rows into ce[base..]
    {
        int p = wbase + inc - cnt;
        #pragma unroll
        for (int u = 0; u < ITILE; ++u) {
            if (flag[u]) { ce[p] = h[u]; ++p; }
        }
    }
    __syncthreads();

    const int K = (C + BLOCK - 1) >> 8;      // ceil(C/256), uniform across block
    float loss = 0.f;
    switch (K) {
        case 1: loss = inner_loop<1>(se, ce, tid, C); break;
        case 2: loss = inner_loop<2>(se, ce, tid, C); break;
        case 3: loss = inner_loop<3>(se, ce, tid, C); break;
        case 4: loss = inner_loop<4>(se, ce, tid, C); break;
        case 5: loss = inner_loop<5>(se, ce, tid, C); break;
        case 6: loss = inner_loop<6>(se, ce, tid, C); break;
        case 7: loss = inner_loop<7>(se, ce, tid, C); break;
        case 8: loss = inner_loop<8>(se, ce, tid, C); break;
        default: break;                       // K==0: no event rows
    }

    for (int off = 32; off; off >>= 1) {
        loss += __shfl_down(loss, off);
        pen  += __shfl_down(pen, off);
    }
    __shared__ float wl[BLOCK / 64], wp[BLOCK / 64];
    if ((tid & 63) == 0) { wl[tid >> 6] = loss; wp[tid >> 6] = pen; }
    __syncthreads();
    if (tid == 0) {
        float tl = 0.f, tp = 0.f;
        for (int w = 0; w < BLOCK / 64; ++w) { tl += wl[w]; tp += wp[w]; }
        lossp[by * nib + bx] = tl;
        if (by == 0) penp[bx] = tp;
    }
}

// Tiny finalize node: fixed-order reduce of partials (deterministic).
__global__ void finalize_kernel(const float* __restrict__ lossp, int nloss,
                                const float* __restrict__ penp, int npen,
                                float* __restrict__ out, int n) {
    const int tid = threadIdx.x;
    const float invn  = 1.0f / (float)n;
    const float invn2 = invn * invn;
    float v = 0.f;
    for (int k = tid; k < nloss; k += BLOCK) v += lossp[k] * invn2;
    for (int k = tid; k < npen;  k += BLOCK) v += penp[k] * invn;
    for (int off = 32; off; off >>= 1) v += __shfl_down(v, off);
    __shared__ float ws[BLOCK / 64];
    if ((tid & 63) == 0) ws[tid >> 6] = v;
    __syncthreads();
    if (tid == 0) {
        float t = 0.f;
        for (int w = 0; w < BLOCK / 64; ++w) t += ws[w];
        out[0] = t;
    }
}

extern "C" void kernel_launch(void* const* d_in, const int* in_sizes, int n_in,
                              void* d_out, int out_size, void* d_ws, size_t ws_size,
                              hipStream_t stream) {
    const float* log_h  = (const float*)d_in[0];
    const float* dur    = (const float*)d_in[1];
    const float* events = (const float*)d_in[2];
    float* out = (float*)d_out;
    const int n = in_sizes[1];                        // 16384

    const int nib = n / (BLOCK * ITILE);              // 8 i-superblocks
    const int njc = n / JCHUNK;                       // 64 j-chunks
    const int nblocks = nib * njc;                    // 512 blocks = 2/CU

    float* lossp = (float*)d_ws;                      // nblocks floats
    float* penp  = lossp + nblocks;                   // nib floats

    pair_fused_kernel<<<nblocks, BLOCK, 0, stream>>>(log_h, dur, events,
                                                     lossp, penp, nib, n);
    finalize_kernel<<<1, BLOCK, 0, stream>>>(lossp, nblocks, penp, nib, out, n);
}